// Round 1
// baseline (303.749 us; speedup 1.0000x reference)
//
#include <hip/hip_runtime.h>
#include <hip/hip_bf16.h>

// Problem constants (from reference)
#define NB 32      // batch
#define NC 8       // channels
#define NL 512     // length
#define NS 63      // scales
#define NK 1009    // max wavelet kernel length (odd)
#define NPAD 504   // (NK-1)/2
#define ND 512     // d_model
#define NCT 512    // total channels after concat = C*(1+S)
#define NROWS 514  // Apad rows per batch (circular-padded: row r = out_feat[(r-1)%512])

typedef __attribute__((ext_vector_type(4))) float f32x4;
typedef __attribute__((ext_vector_type(8))) short short8;
typedef __attribute__((ext_vector_type(4))) float f4;

// Workspace layout (bytes)
#define APAD_BYTES (NB * NROWS * NL * 2)   // 16,842,752  bf16 [B][514][512]
#define WB_BYTES   (3 * ND * NL * 2)       //  1,572,864  bf16 [3][512][512] (W[k][o][l])
#define BANKT_BYTES (NK * 64 * 4)          //    258,304  f32  [1009][64] transposed bank

// ---------------------------------------------------------------------------
// Kernel 1: prep — convert token_w -> bf16 [k][o][l]; transpose bank -> [k][s];
//           cast x channels into Apad rows 1..8 (+ wrap row 513 from ch 0).
// ---------------------------------------------------------------------------
__global__ __launch_bounds__(256) void prep_kernel(
    const float* __restrict__ x, const float* __restrict__ bank,
    const float* __restrict__ tw, __hip_bfloat16* __restrict__ Apad,
    __hip_bfloat16* __restrict__ Wb, float* __restrict__ bankT) {
  const int idx = blockIdx.x * 256 + threadIdx.x;
  const int stride = gridDim.x * 256;

  // 1) Wb[k][o][l] = tw[o][l][k]
  for (int i = idx; i < 3 * ND * NL; i += stride) {
    int k = i / (ND * NL);
    int rem = i - k * (ND * NL);
    int o = rem >> 9;          // /512
    int l = rem & 511;
    Wb[i] = __float2bfloat16(tw[(o * NL + l) * 3 + k]);
  }
  // 2) bankT[k][s] (s padded to 64 with zeros)
  for (int i = idx; i < NK * 64; i += stride) {
    int k = i >> 6;
    int s = i & 63;
    bankT[i] = (s < NS) ? bank[s * NK + k] : 0.f;
  }
  // 3) x -> Apad rows 1+c ; channel 0 also -> wrap row 513
  for (int i = idx; i < NB * NC * NL; i += stride) {
    int b = i >> 12;           // / (8*512)
    int c = (i >> 9) & 7;
    int l = i & 511;
    __hip_bfloat16 v = __float2bfloat16(x[i]);
    Apad[((b * NROWS) + 1 + c) * NL + l] = v;
    if (c == 0) Apad[((b * NROWS) + 513) * NL + l] = v;
  }
}

// ---------------------------------------------------------------------------
// Kernel 2: cwt — per block: one (b,c) row x one 16-scale chunk.
//   conv[s][t] = sum_k bankT[k][s] * x_pad[t+k]   (x_pad zero-padded by 504)
//   then d[t] = |conv[t+1]-conv[t]| (replicate last) -> Apad feat rows (bf16)
// 16 scale-accumulators x 2 t's per thread; taps broadcast (uniform loads).
// ---------------------------------------------------------------------------
__global__ __launch_bounds__(256) void cwt_kernel(
    const float* __restrict__ x, const float* __restrict__ bankT,
    __hip_bfloat16* __restrict__ Apad) {
  const int bc = blockIdx.x >> 2;      // 0..255  (b*8+c)
  const int chunk = blockIdx.x & 3;    // 0..3 (16 scales each; last has 15 real)
  const int tid = threadIdx.x;

  __shared__ float xl[NL + NK - 1];    // 1520 floats
  __shared__ float cv[16][NL];         // conv results for this chunk

  for (int i = tid; i < NL + NK - 1; i += 256) {
    int g = i - NPAD;
    xl[i] = (g >= 0 && g < NL) ? x[bc * NL + g] : 0.f;
  }
  __syncthreads();

  const int sbase = chunk * 16;                   // scale index base (0-based)
  const int smax_scale = (chunk == 3) ? 63 : (sbase + 16);  // largest scale number in chunk
  const int klo = NPAD - 8 * smax_scale;
  const int khi = NPAD + 8 * smax_scale + 1;

  float a0[16], a1[16];
#pragma unroll
  for (int ss = 0; ss < 16; ++ss) { a0[ss] = 0.f; a1[ss] = 0.f; }
  const int t0 = tid, t1 = tid + 256;

  for (int k = klo; k < khi; ++k) {
    float xv0 = xl[t0 + k];
    float xv1 = xl[t1 + k];
    const f4* wp = (const f4*)(bankT + (k << 6) + sbase);  // uniform address
    float w[16];
    *(f4*)(w + 0) = wp[0];
    *(f4*)(w + 4) = wp[1];
    *(f4*)(w + 8) = wp[2];
    *(f4*)(w + 12) = wp[3];
#pragma unroll
    for (int ss = 0; ss < 16; ++ss) {
      a0[ss] = fmaf(w[ss], xv0, a0[ss]);
      a1[ss] = fmaf(w[ss], xv1, a1[ss]);
    }
  }

#pragma unroll
  for (int ss = 0; ss < 16; ++ss) {
    cv[ss][t0] = a0[ss];
    cv[ss][t1] = a1[ss];
  }
  __syncthreads();

  const int nS = (chunk == 3) ? 15 : 16;
  const int b = bc >> 3, c = bc & 7;
  for (int ss = 0; ss < nS; ++ss) {
#pragma unroll
    for (int tt = 0; tt < 2; ++tt) {
      int t = tt ? t1 : t0;
      int ta = (t < NL - 1) ? t : (NL - 2);      // t=511 replicates d[510]
      float dv = fabsf(cv[ss][ta + 1] - cv[ss][ta]);
      int ch = 8 + c * NS + sbase + ss;          // 8..511
      __hip_bfloat16 v = __float2bfloat16(dv);
      Apad[((b * NROWS) + 1 + ch) * NL + t] = v;
      if (ch == NCT - 1)                         // wrap row 0 = out_feat[511]
        Apad[(b * NROWS) * NL + t] = v;
    }
  }
}

// ---------------------------------------------------------------------------
// Kernel 3: gemm — out[b][p][o] = sum_{kap=0..2} sum_l Apad[b][p+kap][l]*Wb[kap][o][l]
// m97-style: 128x128 tile, BK=32, 4 waves, global_load_lds(16B), mfma 16x16x32.
// ---------------------------------------------------------------------------
typedef const __attribute__((address_space(1))) unsigned int* gp1_t;
typedef __attribute__((address_space(3))) unsigned int* lp3_t;

__device__ __forceinline__ void gload_lds16(const void* g, void* l) {
  __builtin_amdgcn_global_load_lds((gp1_t)g, (lp3_t)l, 16, 0, 0);
}

__global__ __launch_bounds__(256) void gemm_kernel(
    const __hip_bfloat16* __restrict__ Ap, const __hip_bfloat16* __restrict__ Wb,
    float* __restrict__ out) {
  __shared__ __hip_bfloat16 sA[128 * 32];
  __shared__ __hip_bfloat16 sB[128 * 32];

  const int tid = threadIdx.x;
  const int b = blockIdx.y;
  const int tile = blockIdx.x;
  const int p0 = (tile & 3) * 128;
  const int o0 = (tile >> 2) * 128;

  const int w = tid >> 6, lane = tid & 63;
  const int wm = w >> 1, wn = w & 1;
  const int row_in = lane & 15, hi = lane >> 4;

  // staging: thread covers 16B chunks q (tid) and q+256 of the 512-chunk tiles
  const int rA0 = tid >> 2, sg0 = tid & 3;           // chunk tid
  const int rA1 = (tid + 256) >> 2, sg1 = (tid + 256) & 3;

  f32x4 acc[4][4] = {};

  for (int kk = 0; kk < 48; ++kk) {
    const int kap = kk >> 4;               // 0..2 (shift)
    const int l0 = (kk & 15) << 5;         // 0..480 step 32

    const __hip_bfloat16* a0p = Ap + ((b * NROWS + p0 + kap + rA0) * NL + l0 + sg0 * 8);
    const __hip_bfloat16* a1p = Ap + ((b * NROWS + p0 + kap + rA1) * NL + l0 + sg1 * 8);
    const __hip_bfloat16* b0p = Wb + ((kap * ND + o0 + rA0) * NL + l0 + sg0 * 8);
    const __hip_bfloat16* b1p = Wb + ((kap * ND + o0 + rA1) * NL + l0 + sg1 * 8);
    gload_lds16(a0p, sA + tid * 8);
    gload_lds16(a1p, sA + (tid + 256) * 8);
    gload_lds16(b0p, sB + tid * 8);
    gload_lds16(b1p, sB + (tid + 256) * 8);

    __syncthreads();   // compiler drains vmcnt before barrier -> LDS tiles ready

    short8 av[4], bv[4];
#pragma unroll
    for (int m = 0; m < 4; ++m)
      av[m] = *(const short8*)(sA + (wm * 64 + m * 16 + row_in) * 32 + hi * 8);
#pragma unroll
    for (int n = 0; n < 4; ++n)
      bv[n] = *(const short8*)(sB + (wn * 64 + n * 16 + row_in) * 32 + hi * 8);

#pragma unroll
    for (int m = 0; m < 4; ++m)
#pragma unroll
      for (int n = 0; n < 4; ++n)
        acc[m][n] = __builtin_amdgcn_mfma_f32_16x16x32_bf16(av[m], bv[n], acc[m][n], 0, 0, 0);

    __syncthreads();   // protect LDS before next staging
  }

  // epilogue: D mapping col=lane&15 (o), row=(lane>>4)*4+reg (p)
#pragma unroll
  for (int m = 0; m < 4; ++m) {
    const int p = p0 + wm * 64 + m * 16 + hi * 4;
#pragma unroll
    for (int n = 0; n < 4; ++n) {
      const int o = o0 + wn * 64 + n * 16 + row_in;
#pragma unroll
      for (int r = 0; r < 4; ++r)
        out[(size_t)((b * NCT) + p + r) * ND + o] = acc[m][n][r];
    }
  }
}

// ---------------------------------------------------------------------------
extern "C" void kernel_launch(void* const* d_in, const int* in_sizes, int n_in,
                              void* d_out, int out_size, void* d_ws, size_t ws_size,
                              hipStream_t stream) {
  const float* x = (const float*)d_in[0];
  const float* bank = (const float*)d_in[1];
  const float* tw = (const float*)d_in[2];
  float* out = (float*)d_out;

  char* ws = (char*)d_ws;
  __hip_bfloat16* Apad = (__hip_bfloat16*)ws;
  __hip_bfloat16* Wb = (__hip_bfloat16*)(ws + APAD_BYTES);
  float* bankT = (float*)(ws + APAD_BYTES + WB_BYTES);

  prep_kernel<<<1024, 256, 0, stream>>>(x, bank, tw, Apad, Wb, bankT);
  cwt_kernel<<<1024, 256, 0, stream>>>(x, bankT, Apad);
  gemm_kernel<<<dim3(16, 32), 256, 0, stream>>>(Apad, Wb, out);
}

// Round 3
// 71.045 us; speedup vs baseline: 4.2754x; 4.2754x over previous
//
#include <hip/hip_runtime.h>
#include <hip/hip_bf16.h>

// Problem constants
#define NB 32      // batch
#define NC 8       // channels
#define NL 512     // length
#define NS 63      // scales
#define NK 1009    // max wavelet kernel length (odd)
#define NPAD 504   // (NK-1)/2
#define ND 512     // d_model
#define NCT 512    // total channels after concat = C*(1+S)
#define NROWS 514  // Apad rows per batch (circular-padded)

typedef __attribute__((ext_vector_type(4))) float f32x4;
typedef __attribute__((ext_vector_type(8))) short short8;
typedef __attribute__((ext_vector_type(4))) short short4v;

// Workspace layout (bytes)
#define APAD_BYTES (NB * NROWS * NL * 2)   // 16,842,752  bf16 [B][514][512]
#define WB_BYTES   (3 * ND * NL * 2)       //  1,572,864  bf16 [3][512][512]
#define BANKB_BYTES (64 * 1024 * 2)        //    131,072  bf16 [64][1024] zero-padded bank

typedef const __attribute__((address_space(1))) unsigned int* gp1_t;
typedef __attribute__((address_space(3))) unsigned int* lp3_t;
__device__ __forceinline__ void gload_lds16(const void* g, void* l) {
  __builtin_amdgcn_global_load_lds((gp1_t)g, (lp3_t)l, 16, 0, 0);
}

__device__ __forceinline__ unsigned short bf16_bits(float v) {
  return __builtin_bit_cast(unsigned short, __float2bfloat16(v));
}

// ---------------------------------------------------------------------------
// Kernel 1: prep — Wb[k][o][l] = bf16(tw[o][l][k]); bankB[s][k] zero-padded bf16;
//           x -> Apad rows 1..8 (+ wrap row 513 from ch 0).
// ---------------------------------------------------------------------------
__global__ __launch_bounds__(256) void prep_kernel(
    const float* __restrict__ x, const float* __restrict__ bank,
    const float* __restrict__ tw, __hip_bfloat16* __restrict__ Apad,
    __hip_bfloat16* __restrict__ Wb, __hip_bfloat16* __restrict__ bankB) {
  const int idx = blockIdx.x * 256 + threadIdx.x;
  const int stride = gridDim.x * 256;

  for (int i = idx; i < 3 * ND * NL; i += stride) {
    int k = i / (ND * NL);
    int rem = i - k * (ND * NL);
    int o = rem >> 9;
    int l = rem & 511;
    Wb[i] = __float2bfloat16(tw[(o * NL + l) * 3 + k]);
  }
  for (int i = idx; i < 64 * 1024; i += stride) {
    int s = i >> 10;
    int k = i & 1023;
    float v = (s < NS && k < NK) ? bank[s * NK + k] : 0.f;
    bankB[i] = __float2bfloat16(v);
  }
  for (int i = idx; i < NB * NC * NL; i += stride) {
    int b = i >> 12;
    int c = (i >> 9) & 7;
    int l = i & 511;
    __hip_bfloat16 v = __float2bfloat16(x[i]);
    Apad[((b * NROWS) + 1 + c) * NL + l] = v;
    if (c == 0) Apad[((b * NROWS) + 513) * NL + l] = v;
  }
}

// ---------------------------------------------------------------------------
// Kernel 2: cwt via MFMA.  Per block (one bc pair):
//   d[t][s] = | sum_k bank[s][k] * dx[t+k] |,  dx[i] = xpad[i+1]-xpad[i]
//   (identity: conv-then-diff == conv-of-differenced-input; t=511 replicates t=510)
// A = bank [64 s][1024 k] bf16, staged in LDS (XOR-swizzled, double-buffered, KT=128).
// B = Toeplitz of dx from 4 shifted LDS copies (r = t&3) -> 8B-aligned reads.
// 8 waves: wave w owns t in [w*64, w*64+64); acc[4 m][4 n] of 16x16 frags.
// ---------------------------------------------------------------------------
#define CPY_STRIDE 3088   // 1536*2 + 16 pad (bank spread across copies)

__global__ __launch_bounds__(512) void cwt_kernel(
    const float* __restrict__ x, const __hip_bfloat16* __restrict__ bankB,
    __hip_bfloat16* __restrict__ Apad) {
  __shared__ char smem[32768 + 4 * CPY_STRIDE];  // 2x16KB bank bufs + 4 dx copies
  char* bankS = smem;
  char* cpy = smem + 32768;

  const int tid = threadIdx.x;
  const int bc = blockIdx.x;
  const int b = bc >> 3, c = bc & 7;
  const int w = tid >> 6, l = tid & 63;
  const int hi = l >> 4, li = l & 15;

  // ---- stage dx copies: cpy[r][e] = bf16(dx[e+r]), e<1536, packed pair writes
  const float* xrow = x + bc * NL;
  for (int i = 0; i < 6; ++i) {
    int p = tid + i * 512;            // 0..3071 = 4 copies x 768 pairs
    int r = p / 768, pe = p - r * 768;
    int e0 = 2 * pe;
    int i0 = e0 + r;                  // dx index of first element
    float xa = (i0 >= NPAD && i0 < NPAD + NL) ? xrow[i0 - NPAD] : 0.f;
    float xb = (i0 + 1 >= NPAD && i0 + 1 < NPAD + NL) ? xrow[i0 + 1 - NPAD] : 0.f;
    float xc = (i0 + 2 >= NPAD && i0 + 2 < NPAD + NL) ? xrow[i0 + 2 - NPAD] : 0.f;
    unsigned short u0 = bf16_bits(xb - xa);
    unsigned short u1 = bf16_bits(xc - xb);
    *(unsigned int*)(cpy + r * CPY_STRIDE + e0 * 2) = (unsigned)u0 | ((unsigned)u1 << 16);
  }

  // ---- stage bank K-tile kt into buf: [64 s][128 k], chunk ^= (s&7) swizzle
  // linear LDS dest + inverse-swizzled global source (both-sides rule)
#define STAGE(kt, buf)                                                        \
  {                                                                           \
    for (int i = 0; i < 2; ++i) {                                             \
      int ck = tid + i * 512;              /* 0..1023 chunks of 16B */        \
      int s_ = ck >> 4, rb = ck & 15;                                         \
      int srcc = rb ^ (s_ & 7);                                               \
      gload_lds16(bankB + s_ * 1024 + (kt) * 128 + srcc * 8,                  \
                  bankS + (buf) * 16384 + ck * 16);                           \
    }                                                                         \
  }

  STAGE(0, 0);
  __syncthreads();  // drains vmcnt+lgkmcnt: dx copies + bank tile 0 ready

  f32x4 acc[4][4] = {};
  const int r = l & 3;                        // t&3 (w*64, n*16 are mult of 4)
  const int tbase = w * 64;
  int buf = 0;

  for (int kt = 0; kt < 8; ++kt) {
    if (kt < 7) STAGE(kt + 1, buf ^ 1);

#pragma unroll
    for (int ksl = 0; ksl < 4; ++ksl) {
      short8 av[4], bv[4];
#pragma unroll
      for (int m = 0; m < 4; ++m) {
        int srow = m * 16 + li;
        int chunk = (ksl * 4 + hi) ^ (srow & 7);
        av[m] = *(const short8*)(bankS + buf * 16384 + srow * 256 + chunk * 16);
      }
#pragma unroll
      for (int n = 0; n < 4; ++n) {
        int t = tbase + n * 16 + li;
        int e = t - r + kt * 128 + ksl * 32 + hi * 8;   // mult of 4
        const char* pc = cpy + r * CPY_STRIDE + e * 2;  // 8B aligned
        short4v lo = *(const short4v*)pc;
        short4v hh = *(const short4v*)(pc + 8);
        short8 f;
        f[0] = lo[0]; f[1] = lo[1]; f[2] = lo[2]; f[3] = lo[3];
        f[4] = hh[0]; f[5] = hh[1]; f[6] = hh[2]; f[7] = hh[3];
        bv[n] = f;
      }
#pragma unroll
      for (int m = 0; m < 4; ++m)
#pragma unroll
        for (int n = 0; n < 4; ++n)
          acc[m][n] = __builtin_amdgcn_mfma_f32_16x16x32_bf16(av[m], bv[n], acc[m][n], 0, 0, 0);
    }

    if (kt < 7) {
      __syncthreads();   // vmcnt(0) drain: next tile staged; all waves done with buf
      buf ^= 1;
    }
  }

  // ---- epilogue: d = |acc| directly (differenced-input identity). No shuffles.
  // lane holds D[s = m*16 + hi*4 + rg][t = w*64 + n*16 + li]
#pragma unroll
  for (int m = 0; m < 4; ++m) {
#pragma unroll
    for (int rg = 0; rg < 4; ++rg) {
      int s = m * 16 + hi * 4 + rg;
      if (s >= NS) continue;               // padded scale row 63: skip
      int ch = 8 + c * NS + s;             // 8..511
      size_t rowbase = ((size_t)(b * NROWS) + 1 + ch) * NL;
#pragma unroll
      for (int n = 0; n < 4; ++n) {
        int t = tbase + n * 16 + li;
        float d = fabsf(acc[m][n][rg]);
        __hip_bfloat16 hv = __float2bfloat16(d);
        bool lastgrp = (w == 7 && n == 3);
        bool skip = lastgrp && (li == 15);     // t=511 slot: value invalid
        bool dup = lastgrp && (li == 14);      // lane14 (t=510) also writes t=511
        if (!skip) Apad[rowbase + t] = hv;
        if (dup) Apad[rowbase + 511] = hv;
        if (ch == NCT - 1) {                   // wrap row 0 = feat channel 511
          size_t wrapbase = (size_t)(b * NROWS) * NL;
          if (!skip) Apad[wrapbase + t] = hv;
          if (dup) Apad[wrapbase + 511] = hv;
        }
      }
    }
  }
#undef STAGE
}

// ---------------------------------------------------------------------------
// Kernel 3: gemm — out[b][p][o] = sum_{kap} sum_l Apad[b][p+kap][l]*Wb[kap][o][l]
// (128x128 tile, BK=32, global_load_lds, mfma 16x16x32)
// ---------------------------------------------------------------------------
__global__ __launch_bounds__(256) void gemm_kernel(
    const __hip_bfloat16* __restrict__ Ap, const __hip_bfloat16* __restrict__ Wb,
    float* __restrict__ out) {
  __shared__ __hip_bfloat16 sA[128 * 32];
  __shared__ __hip_bfloat16 sB[128 * 32];

  const int tid = threadIdx.x;
  const int b = blockIdx.y;
  const int tile = blockIdx.x;
  const int p0 = (tile & 3) * 128;
  const int o0 = (tile >> 2) * 128;

  const int w = tid >> 6, lane = tid & 63;
  const int wm = w >> 1, wn = w & 1;
  const int row_in = lane & 15, hi = lane >> 4;

  const int rA0 = tid >> 2, sg0 = tid & 3;
  const int rA1 = (tid + 256) >> 2, sg1 = (tid + 256) & 3;

  f32x4 acc[4][4] = {};

  for (int kk = 0; kk < 48; ++kk) {
    const int kap = kk >> 4;
    const int l0 = (kk & 15) << 5;

    const __hip_bfloat16* a0p = Ap + ((b * NROWS + p0 + kap + rA0) * NL + l0 + sg0 * 8);
    const __hip_bfloat16* a1p = Ap + ((b * NROWS + p0 + kap + rA1) * NL + l0 + sg1 * 8);
    const __hip_bfloat16* b0p = Wb + ((kap * ND + o0 + rA0) * NL + l0 + sg0 * 8);
    const __hip_bfloat16* b1p = Wb + ((kap * ND + o0 + rA1) * NL + l0 + sg1 * 8);
    gload_lds16(a0p, sA + tid * 8);
    gload_lds16(a1p, sA + (tid + 256) * 8);
    gload_lds16(b0p, sB + tid * 8);
    gload_lds16(b1p, sB + (tid + 256) * 8);

    __syncthreads();

    short8 av[4], bv[4];
#pragma unroll
    for (int m = 0; m < 4; ++m)
      av[m] = *(const short8*)(sA + (wm * 64 + m * 16 + row_in) * 32 + hi * 8);
#pragma unroll
    for (int n = 0; n < 4; ++n)
      bv[n] = *(const short8*)(sB + (wn * 64 + n * 16 + row_in) * 32 + hi * 8);

#pragma unroll
    for (int m = 0; m < 4; ++m)
#pragma unroll
      for (int n = 0; n < 4; ++n)
        acc[m][n] = __builtin_amdgcn_mfma_f32_16x16x32_bf16(av[m], bv[n], acc[m][n], 0, 0, 0);

    __syncthreads();
  }

#pragma unroll
  for (int m = 0; m < 4; ++m) {
    const int p = p0 + wm * 64 + m * 16 + hi * 4;
#pragma unroll
    for (int n = 0; n < 4; ++n) {
      const int o = o0 + wn * 64 + n * 16 + row_in;
#pragma unroll
      for (int r = 0; r < 4; ++r)
        out[(size_t)((b * NCT) + p + r) * ND + o] = acc[m][n][r];
    }
  }
}

// ---------------------------------------------------------------------------
extern "C" void kernel_launch(void* const* d_in, const int* in_sizes, int n_in,
                              void* d_out, int out_size, void* d_ws, size_t ws_size,
                              hipStream_t stream) {
  const float* x = (const float*)d_in[0];
  const float* bank = (const float*)d_in[1];
  const float* tw = (const float*)d_in[2];
  float* out = (float*)d_out;

  char* ws = (char*)d_ws;
  __hip_bfloat16* Apad = (__hip_bfloat16*)ws;
  __hip_bfloat16* Wb = (__hip_bfloat16*)(ws + APAD_BYTES);
  __hip_bfloat16* bankB = (__hip_bfloat16*)(ws + APAD_BYTES + WB_BYTES);

  prep_kernel<<<1024, 256, 0, stream>>>(x, bank, tw, Apad, Wb, bankB);
  cwt_kernel<<<256, 512, 0, stream>>>(x, bankB, Apad);
  gemm_kernel<<<dim3(16, 32), 256, 0, stream>>>(Apad, Wb, out);
}